// Round 8
// baseline (106.877 us; speedup 1.0000x reference)
//
#include <hip/hip_runtime.h>
#include <math.h>

#define NS 24

typedef float v2f __attribute__((ext_vector_type(2)));
typedef float v4f __attribute__((ext_vector_type(4)));

// ws layout (SoA): float partials[5][B] rows = {sp2, st2, spt, mp, mt}

// compile-time table of circle pixels: entries 0..194 in-grid (Voronoi),
// entry 195 = padding pixel (16,24) with label 0. Encoded (yy<<8)|x, yy=y-8.
struct PixTab { unsigned short v[196]; };
__device__ constexpr PixTab make_pix() {
    PixTab t{};
    int n = 0;
    const int w[16] = {0,3,5,6,6,7,7,7,8,7,7,7,6,6,5,3};
    for (int yy = 0; yy < 16; ++yy)
        for (int x = 16 - w[yy]; x <= 16 + w[yy]; ++x)
            if (x < 24) { t.v[n] = (unsigned short)((yy << 8) | x); n = n + 1; }
    t.v[195] = (unsigned short)((8 << 8) | 24);
    return t;
}
__device__ constexpr PixTab PIX = make_pix();

// packed complex mul with w = (c, s):
//   t.re = e.x*c - e.y*s ; t.im = e.x*s + e.y*c
static __device__ __forceinline__ v2f cmul(v2f e, v2f w) {
    v2f m = (v2f){e.y, e.y} * (v2f){w.y, w.x};
    return __builtin_elementwise_fma((v2f){e.x, e.x}, w, (v2f){-m.x, m.y});
}

__global__ __launch_bounds__(256)
void loss_main(const float* __restrict__ output, const float* __restrict__ targets,
               float* __restrict__ partials, int B) {
    __shared__ float2 sxy[NS];
    __shared__ float sp[NS];
    __shared__ float tx[NS], ty[NS], ta[NS];
    __shared__ float2 e24s;                           // phasor(sp[0]) - 1
    __shared__ __align__(16) float gx[NS * 32];       // gaussian x-factors (amp folded in)
    __shared__ __align__(16) float gyT[32 * 24];      // gaussian y-factors, [r][s], stride 24
    __shared__ __align__(16) float e2f[16 * 18 * 2];  // e = phasor-1, [yy][x-8], stride 18 cplx
    __shared__ __align__(16) float tw2f[8 * 32];      // stage-2 twiddles [k0][yp] (c,s)
    __shared__ __align__(16) float gT2f[32 * 36];     // stage-1 out [l][yp] cplx, stride 18 cplx
    __shared__ __align__(16) char uA[5120];           // union: tw1 (2304B) then pm (5120B)
    __shared__ float redm[4][5];

    float* tw1f = (float*)uA;  // stage-1 twiddles [l0][xp] (c,s), stride 18 cplx -- dead after stage 1
    float* pmf  = (float*)uA;  // |pred| fftshifted, stride 40 -- written in stage 2

    const int b = blockIdx.x;
    const int t = threadIdx.x;
    const float* so = output + b * NS * 3;
    const float* tg = targets + b * NS * 3;

    // ---- phase 0: seed/target load + e2 zero-init ----
    if (t < NS) {
        sxy[t] = make_float2(so[3 * t + 0], so[3 * t + 1]);
        sp[t] = so[3 * t + 2];
        if (t == 0) {
            float sv0, cv0;
            __sincosf(6.2831853071795864f * sp[0], &sv0, &cv0);
            e24s = make_float2(cv0 - 1.0f, sv0);
        }
    }
    if (t >= 64 && t < 64 + NS) {
        int s = t - 64;
        tx[s] = tg[3 * s + 0];
        ty[s] = tg[3 * s + 1];
        ta[s] = tg[3 * s + 2];
    }
    for (int i = t; i < 16 * 18; i += 256) *(v2f*)&e2f[i * 2] = (v2f){0.f, 0.f};
    __syncthreads();

    // ---- phase 1a: gaussian factor tables ----
    for (int idx = t; idx < NS * 32; idx += 256) {
        int s = idx >> 5, c = idx & 31;
        float dx = (float)c - tx[s];
        gx[idx] = ta[s] * __expf(dx * dx * (-1.0f / 4.5f));
    }
    for (int idx = t; idx < 32 * 24; idx += 256) {
        int r = idx / 24, s = idx - r * 24;
        float dy = (float)r - ty[s];
        gyT[idx] = __expf(dy * dy * (-1.0f / 4.5f));
    }

    // ---- phase 1t: twiddle tables, exact integer phase (f*x mod 32), (c,s) format ----
    // tw1[l0][xp] = e^{-2pi i l0 (xp+8)/32}, l0 in [0,16), xp in [0,17), stride 18 cplx
    for (int i = t; i < 16 * 18; i += 256) {
        int l0 = i / 18, xp = i - l0 * 18;
        if (xp < 17) {
            int p = (l0 * (xp + 8)) & 31;
            float si, co;
            __sincosf(-(float)p * 0.19634954084936207f, &si, &co);
            *(v2f*)&tw1f[i * 2] = (v2f){co, si};
        }
    }
    // tw2[k0][yp] = e^{-2pi i k0 (yp+8)/32}, k0 in [0,8), yp in [0,16)
    if (t < 128) {
        int k0 = t >> 4, yp = t & 15;
        int p = (k0 * (yp + 8)) & 31;
        float si, co;
        __sincosf(-(float)p * 0.19634954084936207f, &si, &co);
        *(v2f*)&tw2f[k0 * 32 + yp * 2] = (v2f){co, si};
    }

    // ---- phase 1b: packed Voronoi on the 196 circle pixels (squared-dist argmin) ----
    if (t < 196) {
        int pv = (int)PIX.v[t];
        int yy = pv >> 8, x = pv & 255;
        float ph;
        if (t < 195) {
            float fi = (float)yy, fj = (float)(x - 8);
            int best = 0;
            float bd = 1e30f;
#pragma unroll
            for (int s = 0; s < NS; ++s) {
                float2 sv = sxy[s];
                float ddx = fi - sv.x, ddy = fj - sv.y;
                float d2 = ddx * ddx + ddy * ddy;
                if (d2 < bd) { bd = d2; best = s; }
            }
            ph = sp[best];
        } else {
            ph = sp[0];   // padding circle pixel (16,24): label 0
        }
        float sv_, cv_;
        __sincosf(6.2831853071795864f * ph, &sv_, &cv_);
        *(v2f*)&e2f[(yy * 18 + (x - 8)) * 2] = (v2f){cv_ - 1.0f, sv_};
    }
    __syncthreads();

    // ---- stage 1: row DFT over x=8..24, wide LDS loads, packed complex MACs ----
    // thread (yy = t>>4, l0 = t&15) -> outputs l0 (g0) and l0+16 (g1, (-1)^x weights)
    {
        int yy = t >> 4, l0 = t & 15;
        const float* row = &e2f[yy * 36];        // xi = 0 -> x=8
        const float* twr = &tw1f[l0 * 36];
        v2f g0 = {0.f, 0.f}, g1 = {0.f, 0.f};
#pragma unroll
        for (int q = 0; q < 8; ++q) {
            v4f e4 = *(const v4f*)&row[q * 4];   // complex x=8+2q (even), x=9+2q (odd)
            v4f w4 = *(const v4f*)&twr[q * 4];
            v2f ca = cmul((v2f){e4.x, e4.y}, (v2f){w4.x, w4.y});
            v2f cb = cmul((v2f){e4.z, e4.w}, (v2f){w4.z, w4.w});
            g0 += ca + cb;
            g1 += ca - cb;
        }
        {   // tail x = 24 (xp=16, even)
            v2f e16 = *(const v2f*)&row[32];
            v2f w16 = *(const v2f*)&twr[32];
            v2f c16 = cmul(e16, w16);
            g0 += c16; g1 += c16;
        }
        *(v2f*)&gT2f[l0 * 36 + yy * 2] = g0;
        *(v2f*)&gT2f[(l0 + 16) * 36 + yy * 2] = g1;
    }
    __syncthreads();

    // ---- stage 2: col DFT over y=8..23; 4 outputs k=k0+8j via radix-4 combine ----
    {
        int l = t >> 3, k0 = t & 7;
        const float* gTr = &gT2f[l * 36];
        const float* twr = &tw2f[k0 * 32];
        v2f h0 = {0,0}, h1 = {0,0}, h2 = {0,0}, h3 = {0,0};
#pragma unroll
        for (int q = 0; q < 4; ++q) {
            v4f ga = *(const v4f*)&gTr[q * 8];       // yp = 4q, 4q+1
            v4f gb = *(const v4f*)&gTr[q * 8 + 4];   // yp = 4q+2, 4q+3
            v4f wa = *(const v4f*)&twr[q * 8];
            v4f wb = *(const v4f*)&twr[q * 8 + 4];
            v2f t0 = cmul((v2f){ga.x, ga.y}, (v2f){wa.x, wa.y});  // class 0
            v2f t1 = cmul((v2f){ga.z, ga.w}, (v2f){wa.z, wa.w});  // class 1
            v2f t2 = cmul((v2f){gb.x, gb.y}, (v2f){wb.x, wb.y});  // class 2
            v2f t3 = cmul((v2f){gb.z, gb.w}, (v2f){wb.z, wb.w});  // class 3
            v2f a = t0 + t2, bb = t0 - t2;
            v2f c = t1 + t3, d = t1 - t3;
            v2f du = {d.y, -d.x};                                 // d * (-i)
            h0 += a + c;
            h1 += bb + du;
            h2 += a - c;
            h3 += bb - du;
        }
        {   // analytic pixel (24,16): e24 * (-1)^l * i^k0  (same for all j: i^(8j)=1)
            float2 e24 = e24s;
            int m = k0 & 3;
            float ar2 = (m == 0) ? 1.f : (m == 2) ? -1.f : 0.f;  // i^k0
            float ai2 = (m == 1) ? 1.f : (m == 3) ? -1.f : 0.f;
            float sgn = (l & 1) ? -1.f : 1.f;
            v2f T = {sgn * (e24.x * ar2 - e24.y * ai2),
                     sgn * (e24.x * ai2 + e24.y * ar2)};
            h0 += T; h1 += T; h2 += T; h3 += T;
        }
        if (t == 0) h0.x += 1024.0f;   // FFT(ones) delta at (k,l)=(0,0)
        int v = (l + 16) & 31;
        v2f q0 = h0 * h0, q1 = h1 * h1, q2 = h2 * h2, q3 = h3 * h3;
        pmf[((k0 + 16) & 31) * 40 + v] = sqrtf(q0.x + q0.y);
        pmf[((k0 + 24) & 31) * 40 + v] = sqrtf(q1.x + q1.y);
        pmf[(k0)        * 40 + v]      = sqrtf(q2.x + q2.y);
        pmf[(k0 + 8)    * 40 + v]      = sqrtf(q3.x + q3.y);
    }
    __syncthreads();

    // ---- target + block reductions: 4 consecutive pixels per thread, packed FMAs ----
    float mp, mt, sp2, st2, spt;
    {
        int r = t >> 3;
        int c0 = (t & 7) * 4;
        v4f p4 = *(const v4f*)&pmf[r * 40 + c0];
        v2f t01 = {0.f, 0.f}, t23 = {0.f, 0.f};
#pragma unroll
        for (int q = 0; q < 6; ++q) {
            v4f gy4 = *(const v4f*)&gyT[r * 24 + q * 4];   // gy for seeds 4q..4q+3
#pragma unroll
            for (int j = 0; j < 4; ++j) {
                int s = 4 * q + j;
                v4f g4 = *(const v4f*)&gx[s * 32 + c0];
                float gyv = (j == 0) ? gy4.x : (j == 1) ? gy4.y : (j == 2) ? gy4.z : gy4.w;
                v2f gv = {gyv, gyv};
                t01 = __builtin_elementwise_fma(gv, (v2f){g4.x, g4.y}, t01);
                t23 = __builtin_elementwise_fma(gv, (v2f){g4.z, g4.w}, t23);
            }
        }
        v2f p01 = {p4.x, p4.y}, p23 = {p4.z, p4.w};
        v2f s2v = __builtin_elementwise_fma(p23, p23, p01 * p01);
        v2f t2v = __builtin_elementwise_fma(t23, t23, t01 * t01);
        v2f ptv = __builtin_elementwise_fma(p23, t23, p01 * t01);
        sp2 = s2v.x + s2v.y;
        st2 = t2v.x + t2v.y;
        spt = ptv.x + ptv.y;
        mp = fmaxf(fmaxf(p4.x, p4.y), fmaxf(p4.z, p4.w));
        mt = fmaxf(fmaxf(t01.x, t01.y), fmaxf(t23.x, t23.y));
    }

    for (int off = 32; off > 0; off >>= 1) {
        mp  = fmaxf(mp, __shfl_down(mp, off));
        mt  = fmaxf(mt, __shfl_down(mt, off));
        sp2 += __shfl_down(sp2, off);
        st2 += __shfl_down(st2, off);
        spt += __shfl_down(spt, off);
    }
    int wave = t >> 6, lane = t & 63;
    if (lane == 0) {
        redm[wave][0] = sp2; redm[wave][1] = st2; redm[wave][2] = spt;
        redm[wave][3] = mp;  redm[wave][4] = mt;
    }
    __syncthreads();
    if (t == 0) {
        for (int w = 1; w < 4; ++w) {
            sp2 += redm[w][0];
            st2 += redm[w][1];
            spt += redm[w][2];
            mp = fmaxf(mp, redm[w][3]);
            mt = fmaxf(mt, redm[w][4]);
        }
        // plain stores -- NO atomics, NO fences (round-4 lesson: contended
        // same-line device atomics serialize at ~12ns each).
        partials[0 * B + b] = sp2;
        partials[1 * B + b] = st2;
        partials[2 * B + b] = spt;
        partials[3 * B + b] = mp;
        partials[4 * B + b] = mt;
    }
}

__global__ __launch_bounds__(1024)
void finalize_loss(const float* __restrict__ partials, float* __restrict__ out, int B) {
    __shared__ double reds[16][3];
    __shared__ float redx[16][2];
    const int t = threadIdx.x;
    double sp2 = 0.0, st2 = 0.0, spt = 0.0;
    float mp = 0.f, mt = 0.f;
    for (int i = t; i < B; i += 1024) {
        sp2 += (double)partials[0 * B + i];
        st2 += (double)partials[1 * B + i];
        spt += (double)partials[2 * B + i];
        mp = fmaxf(mp, partials[3 * B + i]);
        mt = fmaxf(mt, partials[4 * B + i]);
    }
    for (int off = 32; off > 0; off >>= 1) {
        sp2 += __shfl_down(sp2, off);
        st2 += __shfl_down(st2, off);
        spt += __shfl_down(spt, off);
        mp = fmaxf(mp, __shfl_down(mp, off));
        mt = fmaxf(mt, __shfl_down(mt, off));
    }
    int wave = t >> 6, lane = t & 63;
    if (lane == 0) {
        reds[wave][0] = sp2; reds[wave][1] = st2; reds[wave][2] = spt;
        redx[wave][0] = mp;  redx[wave][1] = mt;
    }
    __syncthreads();
    if (t == 0) {
        for (int w = 1; w < 16; ++w) {
            sp2 += reds[w][0];
            st2 += reds[w][1];
            spt += reds[w][2];
            mp = fmaxf(mp, redx[w][0]);
            mt = fmaxf(mt, redx[w][1]);
        }
        double Mp = (double)mp, Mt = (double)mt;
        double loss = (sp2 * (Mt / Mp) + st2 * (Mp / Mt) - 2.0 * spt) / sqrt(sp2 * st2);
        out[0] = (float)loss;
    }
}

extern "C" void kernel_launch(void* const* d_in, const int* in_sizes, int n_in,
                              void* d_out, int out_size, void* d_ws, size_t ws_size,
                              hipStream_t stream) {
    const float* output  = (const float*)d_in[0];
    const float* targets = (const float*)d_in[1];
    int B = in_sizes[0] / (NS * 3);
    float* partials = (float*)d_ws;     // 5*B floats

    loss_main<<<B, 256, 0, stream>>>(output, targets, partials, B);
    finalize_loss<<<1, 1024, 0, stream>>>(partials, (float*)d_out, B);
}